// Round 1
// 231.241 us; speedup vs baseline: 1.0078x; 1.0078x over previous
//
#include <hip/hip_runtime.h>

#define NN 1024
#define HH 512
#define TR 32
#define TC 32
#define S1R 70          // stage-1 rows needed: 2*(TR-1)+8
#define XST 74          // EVEN -> 8B-aligned b64 window reads; banks (10u+8cg+2t)%32 = 4 lanes/pair (free)
#define NF4 18          // float4 loads per row (logical cols 0..71)
#define NLD ((S1R * NF4 + 255) / 256)   // 5 load iters per thread
#define ADS 36          // A/D plane stride: mult-of-4 -> b128-aligned; quad-group (9*row+cg)%8 uniform (free)

typedef float f2  __attribute__((ext_vector_type(2)));
typedef float f4v __attribute__((ext_vector_type(4)));

// acc.lo += ab.lo*w.lo ; acc.hi += ab.hi*w.lo   (broadcast LOW half of w)
__device__ __forceinline__ void pk_fma_blo(f2& acc, f2 ab, f2 w) {
    asm("v_pk_fma_f32 %0, %1, %2, %0 op_sel:[0,0,0] op_sel_hi:[1,0,1]"
        : "+v"(acc) : "v"(ab), "v"(w));
}
// acc.lo += ab.lo*w.hi ; acc.hi += ab.hi*w.hi   (broadcast HIGH half of w)
__device__ __forceinline__ void pk_fma_bhi(f2& acc, f2 ab, f2 w) {
    asm("v_pk_fma_f32 %0, %1, %2, %0 op_sel:[0,1,0] op_sel_hi:[1,1,1]"
        : "+v"(acc) : "v"(ab), "v"(w));
}

__global__ __launch_bounds__(256, 4) void dwt2d_fused(const float* __restrict__ x,
                                                      const float* __restrict__ bmt,
                                                      float* __restrict__ out) {
    __shared__ float Xs[S1R][XST];   // 70 x 74 x 4B = 20,720 B  (physical col = logical col - 1)
    __shared__ float As[S1R][ADS];   // 70 x 36 x 4B = 10,080 B
    __shared__ float Ds[S1R][ADS];   // 70 x 36 x 4B = 10,080 B   (total 40,880 -> 4 blk/CU)

    const int tid = threadIdx.x;
    const int b  = blockIdx.z;
    const int R0 = blockIdx.y * TR;
    const int C0 = blockIdx.x * TC;

    // lohi[j] = (dec_lo[j], dec_hi[j]); dec_lo[j]=bmt[7-j], dec_hi[j]=bmt[j]*(j odd ? +1 : -1)
    f2 lohi[8];
#pragma unroll
    for (int j = 0; j < 8; ++j) {
        float l = bmt[7 - j];
        float v = bmt[j];
        f2 p; p.x = l; p.y = (j & 1) ? v : -v;
        lohi[j] = p;
    }

    const float* xb = x + (size_t)b * NN * NN;
    const int rbase = 2 * R0 - 3;        // patch row u -> x row (rbase+u) & 1023
    const int pb    = 2 * C0 - 4;        // logical patch col p -> x col (pb+p) & 1023 (f4-aligned)

    // ---- phase 1: load 70 x 18 float4s (wrapped, aligned, unconditional), store SHIFTED by -1.
    float4 v[NLD];
    int    su[NLD], st4[NLD];
#pragma unroll
    for (int k = 0; k < NLD; ++k) {
        int idx = tid + 256 * k;
        unsigned uu = (unsigned)idx / 18u;
        int tt = idx - 18 * (int)uu;
        su[k] = (int)uu; st4[k] = tt;
        int row = (rbase + (int)uu) & (NN - 1);
        int gc  = (pb + 4 * tt) & (NN - 1);
        v[k] = *(const float4*)(xb + ((size_t)row << 10) + gc);
    }
#pragma unroll
    for (int k = 0; k < NLD; ++k) {
        int idx = tid + 256 * k;
        if (idx < S1R * NF4) {
            int u = su[k];
            int q = 4 * st4[k] - 1;              // physical base (logical 4t -> physical 4t-1)
            if (q >= 0) Xs[u][q] = v[k].x;       // drop logical col 0 (never used)
            f2 yz; yz.x = v[k].y; yz.y = v[k].z;
            *(f2*)&Xs[u][q + 1] = yz;            // q+1 = 4t: 8B-aligned b64 write
            Xs[u][q + 3] = v[k].w;               // q+3 = 4t+2 (<=70, inside XST pad)
        }
    }
    __syncthreads();

    // ---- phase 2: stage-1 filter. Output c0+m needs physical cols 2(c0+m)..2(c0+m)+7.
    // Window = 7 aligned float2s; packed (a,d) accumulation; quad b128 stores to A/D planes.
    for (int pos = tid; pos < S1R * 8; pos += 256) {
        int u  = pos >> 3;
        int c0 = (pos & 7) * 4;
        const f2* wrow = (const f2*)&Xs[u][2 * c0];     // even offset -> 8B aligned
        f2 w2[7];
#pragma unroll
        for (int t = 0; t < 7; ++t) w2[t] = wrow[t];
        f2 accs[4];
#pragma unroll
        for (int m = 0; m < 4; ++m) {
            f2 acc; acc.x = 0.f; acc.y = 0.f;
#pragma unroll
            for (int s = 0; s < 4; ++s) {
                pk_fma_blo(acc, lohi[2 * s],     w2[m + s]);   // j=2s   tap (w.x)
                pk_fma_bhi(acc, lohi[2 * s + 1], w2[m + s]);   // j=2s+1 tap (w.y)
            }
            accs[m] = acc;
        }
        f4v va, vd;
        va.x = accs[0].x; va.y = accs[1].x; va.z = accs[2].x; va.w = accs[3].x;
        vd.x = accs[0].y; vd.y = accs[1].y; vd.z = accs[2].y; vd.w = accs[3].y;
        *(f4v*)&As[u][c0] = va;                 // b128, quad-group (9u+cg)%8 uniform -> free
        *(f4v*)&Ds[u][c0] = vd;
    }
    __syncthreads();

    // ---- phase 3: stage-2 filter (along rows); 4 quadrants. One b128 per plane per tap.
    const int cg = tid & 7;
    const int r  = tid >> 3;
    f2 acc0[4], acc1[4];                        // acc0[i]=(aa,ad), acc1[i]=(da,dd)
#pragma unroll
    for (int i = 0; i < 4; ++i) {
        acc0[i].x = 0.f; acc0[i].y = 0.f;
        acc1[i].x = 0.f; acc1[i].y = 0.f;
    }
#pragma unroll
    for (int j = 0; j < 8; ++j) {
        f4v qa = *(const f4v*)&As[2 * r + j][4 * cg];   // quad-group (2r+j+cg)%8 uniform -> free
        f4v qd = *(const f4v*)&Ds[2 * r + j][4 * cg];
        f2 lh = lohi[j];
        f2 a01 = qa.xy, a23 = qa.zw, d01 = qd.xy, d23 = qd.zw;
        pk_fma_blo(acc0[0], lh, a01);   // (aa,ad) += (lo,hi)*A[..][4cg+0]
        pk_fma_bhi(acc0[1], lh, a01);
        pk_fma_blo(acc0[2], lh, a23);
        pk_fma_bhi(acc0[3], lh, a23);
        pk_fma_blo(acc1[0], lh, d01);   // (da,dd) += (lo,hi)*D[..][4cg+0]
        pk_fma_bhi(acc1[1], lh, d01);
        pk_fma_blo(acc1[2], lh, d23);
        pk_fma_bhi(acc1[3], lh, d23);
    }
    float* ob = out + (size_t)b * NN * NN;
    const int orow = R0 + r;
    const int ocol = C0 + 4 * cg;
    *(float4*)(ob + (size_t)orow * NN + ocol)             = make_float4(acc0[0].x, acc0[1].x, acc0[2].x, acc0[3].x);
    *(float4*)(ob + (size_t)orow * NN + ocol + HH)        = make_float4(acc0[0].y, acc0[1].y, acc0[2].y, acc0[3].y);
    *(float4*)(ob + (size_t)(orow + HH) * NN + ocol)      = make_float4(acc1[0].x, acc1[1].x, acc1[2].x, acc1[3].x);
    *(float4*)(ob + (size_t)(orow + HH) * NN + ocol + HH) = make_float4(acc1[0].y, acc1[1].y, acc1[2].y, acc1[3].y);
}

extern "C" void kernel_launch(void* const* d_in, const int* in_sizes, int n_in,
                              void* d_out, int out_size, void* d_ws, size_t ws_size,
                              hipStream_t stream) {
    const float* x   = (const float*)d_in[0];
    const float* bmt = (const float*)d_in[1];
    float* out = (float*)d_out;
    const int B = in_sizes[0] / (NN * NN);   // 32
    dim3 grid(HH / TC, HH / TR, B);          // 16 x 16 x 32
    dwt2d_fused<<<grid, 256, 0, stream>>>(x, bmt, out);
}